// Round 1
// baseline (731.710 us; speedup 1.0000x reference)
//
#include <hip/hip_runtime.h>
#include <cmath>

#define B 64
#define S 400
#define H 512
#define E 256
#define V 50000
#define OOV 100
#define H2 1024         // 2H
#define VDN (V + OOV)   // 50100

__device__ __forceinline__ float wred_sum(float v) {
#pragma unroll
  for (int o = 32; o > 0; o >>= 1) v += __shfl_down(v, o, 64);
  return v;
}
__device__ __forceinline__ float wred_max(float v) {
#pragma unroll
  for (int o = 32; o > 0; o >>= 1) v = fmaxf(v, __shfl_down(v, o, 64));
  return v;
}

// ---------------- embedding gather: Ax[b][k] = emb[summaries_in[b]][k] ----------
__global__ __launch_bounds__(256) void k_packx(const float* __restrict__ emb,
                                               const int* __restrict__ sumin,
                                               float* __restrict__ Ax) {
  Ax[blockIdx.x * E + threadIdx.x] =
      emb[(size_t)sumin[blockIdx.x] * E + threadIdx.x];
}

// ---------------- generic skinny GEMM: out[b][j] (+)= sum_k A[b][k]*W[j][k] + b1[j]+b2[j]
// block: 16 j x 64 b, threads (64,4), each thread 4 j. K multiple of 64, N multiple of 16.
__global__ __launch_bounds__(256) void k_gemm16(
    const float* __restrict__ A, int lda, const float* __restrict__ W, int ldw,
    const float* __restrict__ b1, const float* __restrict__ b2,
    float* __restrict__ out, int N, int K, int accum) {
  __shared__ float As[B][65];
  const int lane = threadIdx.x;  // b
  const int jg = threadIdx.y;    // 0..3
  const int j0 = blockIdx.x * 16 + jg * 4;
  const int t = jg * 64 + lane;
  float acc[4] = {0.f, 0.f, 0.f, 0.f};
  for (int kc = 0; kc < K; kc += 64) {
    __syncthreads();
#pragma unroll
    for (int i = 0; i < 16; ++i) {
      int idx = i * 256 + t;
      As[idx >> 6][idx & 63] = A[(size_t)(idx >> 6) * lda + kc + (idx & 63)];
    }
    __syncthreads();
    for (int kk = 0; kk < 64; kk += 4) {
      float4 w0 = *(const float4*)&W[(size_t)(j0 + 0) * ldw + kc + kk];
      float4 w1 = *(const float4*)&W[(size_t)(j0 + 1) * ldw + kc + kk];
      float4 w2 = *(const float4*)&W[(size_t)(j0 + 2) * ldw + kc + kk];
      float4 w3 = *(const float4*)&W[(size_t)(j0 + 3) * ldw + kc + kk];
#pragma unroll
      for (int u = 0; u < 4; ++u) {
        float av = As[lane][kk + u];
        acc[0] += av * reinterpret_cast<const float*>(&w0)[u];
        acc[1] += av * reinterpret_cast<const float*>(&w1)[u];
        acc[2] += av * reinterpret_cast<const float*>(&w2)[u];
        acc[3] += av * reinterpret_cast<const float*>(&w3)[u];
      }
    }
  }
#pragma unroll
  for (int jj = 0; jj < 4; ++jj) {
    int j = j0 + jj;
    float bias = 0.f;
    if (b1) bias += b1[j];
    if (b2) bias += b2[j];
    float prev = accum ? out[(size_t)lane * N + j] : 0.f;
    out[(size_t)lane * N + j] = prev + acc[jj] + bias;
  }
}

// ---------------- LSTM pointwise -> hidden_out = [h | c] -----------------------
__global__ __launch_bounds__(256) void k_lstm(const float* __restrict__ gates,
                                              const float* __restrict__ c0,
                                              float* __restrict__ hidden) {
  int idx = blockIdx.x * 256 + threadIdx.x;  // 64*512
  int b = idx >> 9, u = idx & 511;
  float gi = gates[(size_t)b * 2048 + u];
  float gf = gates[(size_t)b * 2048 + 512 + u];
  float gg = gates[(size_t)b * 2048 + 1024 + u];
  float go = gates[(size_t)b * 2048 + 1536 + u];
  float si = 1.f / (1.f + expf(-gi));
  float sf = 1.f / (1.f + expf(-gf));
  float so = 1.f / (1.f + expf(-go));
  float c = sf * c0[(size_t)b * 512 + u] + si * tanhf(gg);
  float h = so * tanhf(c);
  hidden[(size_t)b * H2 + u] = h;
  hidden[(size_t)b * H2 + 512 + u] = c;
}

// ---------------- attention scores e[s,b] -------------------------------------
__global__ __launch_bounds__(128) void k_e(
    const float* __restrict__ ef, const float* __restrict__ dfeat,
    const float* __restrict__ cov, const float* __restrict__ Wcov,
    const float* __restrict__ bcov, const float* __restrict__ watt,
    const float* __restrict__ batt, float* __restrict__ e_out) {
  const int sb = blockIdx.x;       // s*64+b
  const int b = sb & 63;
  const float cval = cov[sb];
  const float4* efr = (const float4*)(ef + (size_t)sb * H2);
  const float4* dfr = (const float4*)(dfeat + (size_t)b * H2);
  const float4* wcr = (const float4*)Wcov;
  const float4* bcr = (const float4*)bcov;
  const float4* war = (const float4*)watt;
  float sum = 0.f;
#pragma unroll
  for (int i = 0; i < 2; ++i) {
    int d4 = threadIdx.x + i * 128;
    float4 ev = efr[d4], dv = dfr[d4], wc = wcr[d4], bc = bcr[d4], wa = war[d4];
    sum += tanhf(ev.x + dv.x + cval * wc.x + bc.x) * wa.x;
    sum += tanhf(ev.y + dv.y + cval * wc.y + bc.y) * wa.y;
    sum += tanhf(ev.z + dv.z + cval * wc.z + bc.z) * wa.z;
    sum += tanhf(ev.w + dv.w + cval * wc.w + bc.w) * wa.w;
  }
  sum = wred_sum(sum);
  __shared__ float ls[2];
  if ((threadIdx.x & 63) == 0) ls[threadIdx.x >> 6] = sum;
  __syncthreads();
  if (threadIdx.x == 0) e_out[sb] = ls[0] + ls[1] + batt[0];
}

// ---------------- masked softmax over s + coverage update ----------------------
__global__ __launch_bounds__(512) void k_soft(const float* __restrict__ e,
                                              const float* __restrict__ mask,
                                              const float* __restrict__ cov_in,
                                              float* __restrict__ a_out,
                                              float* __restrict__ cov_out) {
  const int b = blockIdx.x;
  const int s = threadIdx.x;
  __shared__ float red[8];
  float ev = (s < S) ? e[s * B + b] : -INFINITY;
  float m = wred_max(ev);
  if ((s & 63) == 0) red[s >> 6] = m;
  __syncthreads();
  if (s == 0) {
    float mm = red[0];
#pragma unroll
    for (int i = 1; i < 8; ++i) mm = fmaxf(mm, red[i]);
    red[0] = mm;
  }
  __syncthreads();
  m = red[0];
  float ex = (s < S) ? mask[s * B + b] * expf(ev - m) : 0.f;
  float ws = wred_sum(ex);
  __syncthreads();
  if ((s & 63) == 0) red[s >> 6] = ws;
  __syncthreads();
  if (s == 0) {
    float z = 0.f;
#pragma unroll
    for (int i = 0; i < 8; ++i) z += red[i];
    red[0] = z;
  }
  __syncthreads();
  float Z = red[0];
  if (s < S) {
    float av = ex / Z;
    a_out[s * B + b] = av;
    cov_out[s * B + b] = cov_in[s * B + b] + av;
  }
}

// ---------------- ctx_new partial: part[sc][b][d] = sum_{s in chunk} a*enc -----
__global__ __launch_bounds__(256) void k_ctxp(const float* __restrict__ a,
                                              const float* __restrict__ enc,
                                              float* __restrict__ part) {
  const int b = blockIdx.x & 63;
  const int sc = blockIdx.x >> 6;
  const int d = threadIdx.x * 4;
  float4 acc = make_float4(0.f, 0.f, 0.f, 0.f);
  for (int s = sc * 50; s < sc * 50 + 50; ++s) {
    float av = a[s * B + b];
    float4 ev = *(const float4*)(enc + ((size_t)b * S + s) * H2 + d);
    acc.x += av * ev.x;
    acc.y += av * ev.y;
    acc.z += av * ev.z;
    acc.w += av * ev.w;
  }
  *(float4*)(part + (size_t)blockIdx.x * H2 + d) = acc;
}

__global__ __launch_bounds__(256) void k_ctxred(const float* __restrict__ part,
                                                float* __restrict__ ctx_new) {
  int idx = blockIdx.x * 256 + threadIdx.x;  // 65536
  float s = 0.f;
#pragma unroll
  for (int sc = 0; sc < 8; ++sc) s += part[(size_t)sc * 65536 + idx];
  ctx_new[idx] = s;
}

// ---------------- p_gen -------------------------------------------------------
__global__ __launch_bounds__(256) void k_pgen(
    const float* __restrict__ ctx_new, const float* __restrict__ hidden,
    const float* __restrict__ ctx_out, const float* __restrict__ Wpg,
    const float* __restrict__ bpg, float* __restrict__ pgen) {
  const int b = blockIdx.x;
  float p = 0.f;
  for (int k = threadIdx.x; k < 2304; k += 256) {
    float v = (k < 1024) ? ctx_new[(size_t)b * H2 + k]
              : (k < 2048) ? hidden[(size_t)b * H2 + k - 1024]
                           : ctx_out[(size_t)b * E + k - 2048];
    p += v * Wpg[k];
  }
  p = wred_sum(p);
  __shared__ float red[4];
  if ((threadIdx.x & 63) == 0) red[threadIdx.x >> 6] = p;
  __syncthreads();
  if (threadIdx.x == 0) {
    float d = red[0] + red[1] + red[2] + red[3] + bpg[0];
    pgen[b] = 1.f / (1.f + expf(-d));
  }
}

// ---------------- row max + sumexp over V --------------------------------------
__global__ __launch_bounds__(256) void k_rowstats(const float* __restrict__ logits,
                                                  float* __restrict__ mz) {
  const int b = blockIdx.x;
  float m = -INFINITY;
  for (int v = threadIdx.x; v < V; v += 256) m = fmaxf(m, logits[(size_t)b * V + v]);
  m = wred_max(m);
  __shared__ float red[4];
  if ((threadIdx.x & 63) == 0) red[threadIdx.x >> 6] = m;
  __syncthreads();
  float M = fmaxf(fmaxf(red[0], red[1]), fmaxf(red[2], red[3]));
  float sm = 0.f;
  for (int v = threadIdx.x; v < V; v += 256) sm += expf(logits[(size_t)b * V + v] - M);
  sm = wred_sum(sm);
  __syncthreads();
  if ((threadIdx.x & 63) == 0) red[threadIdx.x >> 6] = sm;
  __syncthreads();
  if (threadIdx.x == 0) {
    mz[b] = M;
    mz[64 + b] = red[0] + red[1] + red[2] + red[3];
  }
}

// ---------------- vd = p_gen * softmax(logits), zero OOV tail ------------------
__global__ __launch_bounds__(256) void k_vd(const float* __restrict__ logits,
                                            const float* __restrict__ mz,
                                            const float* __restrict__ pgen,
                                            float* __restrict__ out) {
  const int b = blockIdx.x;
  const float M = mz[b];
  const float scale = pgen[b] / mz[64 + b];
  for (int v = threadIdx.x; v < VDN; v += 256) {
    float val = (v < V) ? scale * expf(logits[(size_t)b * V + v] - M) : 0.f;
    out[(size_t)b * VDN + v] = val;
  }
}

// ---------------- scatter-add copy distribution --------------------------------
__global__ __launch_bounds__(256) void k_scatter(const float* __restrict__ a,
                                                 const int* __restrict__ tex,
                                                 const float* __restrict__ pgen,
                                                 float* __restrict__ vd) {
  int g = blockIdx.x * 256 + threadIdx.x;
  if (g >= S * B) return;
  int b = g & 63;
  float w = (1.f - pgen[b]) * a[g];
  atomicAdd(&vd[(size_t)b * VDN + tex[g]], w);
}

extern "C" void kernel_launch(void* const* d_in, const int* in_sizes, int n_in,
                              void* d_out, int out_size, void* d_ws, size_t ws_size,
                              hipStream_t stream) {
  const int* sumin = (const int*)d_in[0];
  const float* h0 = (const float*)d_in[1];
  const float* c0 = (const float*)d_in[2];
  const float* enc_out = (const float*)d_in[3];
  const float* ef = (const float*)d_in[4];
  const float* mask = (const float*)d_in[5];
  const float* context = (const float*)d_in[6];
  const float* coverage = (const float*)d_in[7];
  const int* tex = (const int*)d_in[8];
  const float* emb = (const float*)d_in[10];
  const float* W_feat = (const float*)d_in[11];
  const float* b_feat = (const float*)d_in[12];
  const float* W_cov = (const float*)d_in[13];
  const float* b_cov = (const float*)d_in[14];
  const float* w_att = (const float*)d_in[15];
  const float* b_att = (const float*)d_in[16];
  const float* W_ih = (const float*)d_in[17];
  const float* W_hh = (const float*)d_in[18];
  const float* b_ih = (const float*)d_in[19];
  const float* b_hh = (const float*)d_in[20];
  const float* W_ctx = (const float*)d_in[21];
  const float* b_ctx = (const float*)d_in[22];
  const float* W_pg = (const float*)d_in[23];
  const float* b_pg = (const float*)d_in[24];
  const float* W_o1 = (const float*)d_in[25];
  const float* b_o1 = (const float*)d_in[26];
  const float* W_o2 = (const float*)d_in[27];
  const float* b_o2 = (const float*)d_in[28];

  float* out = (float*)d_out;
  float* vd = out;                               // [64][50100]
  float* hidden = vd + (size_t)B * VDN;          // [64][1024] = [h|c]
  float* ctx_new = hidden + (size_t)B * H2;      // [64][1024]
  float* a_out = ctx_new + (size_t)B * H2;       // [400][64]
  float* cov_out = a_out + (size_t)S * B;        // [400][64]

  float* ws = (float*)d_ws;
  size_t o = 0;
  float* Ax = ws + o;      o += (size_t)B * E;        // 16384
  float* ctx_out = ws + o; o += (size_t)B * E;        // 16384
  float* gates = ws + o;   o += (size_t)B * 2048;     // 131072
  float* dfeat = ws + o;   o += (size_t)B * H2;       // 65536
  float* e_ws = ws + o;    o += (size_t)S * B;        // 25600
  float* part = ws + o;    o += (size_t)8 * B * H2;   // 524288
  float* inner = ws + o;   o += (size_t)B * 512;      // 32768
  float* pgen = ws + o;    o += 64;
  float* mz = ws + o;      o += 128;
  float* logits = ws + o;  o += (size_t)B * V;        // 3200000

  dim3 gblk(64, 4);

  // x = emb[summaries_in]
  k_packx<<<B, 256, 0, stream>>>(emb, sumin, Ax);
  // ctx_out = [context | x] @ W_ctx.T + b_ctx
  k_gemm16<<<E / 16, gblk, 0, stream>>>(context, H2, W_ctx, 1280, b_ctx, nullptr,
                                        ctx_out, E, 1024, 0);
  k_gemm16<<<E / 16, gblk, 0, stream>>>(Ax, E, W_ctx + 1024, 1280, nullptr, nullptr,
                                        ctx_out, E, 256, 1);
  // gates = ctx_out@W_ih.T + b_ih + h0@W_hh.T + b_hh
  k_gemm16<<<2048 / 16, gblk, 0, stream>>>(ctx_out, E, W_ih, 256, b_ih, b_hh,
                                           gates, 2048, 256, 0);
  k_gemm16<<<2048 / 16, gblk, 0, stream>>>(h0, 512, W_hh, 512, nullptr, nullptr,
                                           gates, 2048, 512, 1);
  // LSTM pointwise -> hidden_out = [h|c]
  k_lstm<<<(B * 512) / 256, 256, 0, stream>>>(gates, c0, hidden);
  // dec_feat = hidden_out @ W_feat.T + b_feat
  k_gemm16<<<H2 / 16, gblk, 0, stream>>>(hidden, H2, W_feat, H2, b_feat, nullptr,
                                         dfeat, H2, H2, 0);
  // attention scores
  k_e<<<S * B, 128, 0, stream>>>(ef, dfeat, coverage, W_cov, b_cov, w_att, b_att, e_ws);
  // masked softmax + renorm + coverage update (writes a and coverage_next outputs)
  k_soft<<<B, 512, 0, stream>>>(e_ws, mask, coverage, a_out, cov_out);
  // ctx_new = einsum(a, encoder_out), split-S deterministic reduction
  k_ctxp<<<8 * B, 256, 0, stream>>>(a_out, enc_out, part);
  k_ctxred<<<(B * H2) / 256, 256, 0, stream>>>(part, ctx_new);
  // p_gen
  k_pgen<<<B, 256, 0, stream>>>(ctx_new, hidden, ctx_out, W_pg, b_pg, pgen);
  // inner = [h | ctx_new] @ W_o1.T + b_o1
  k_gemm16<<<512 / 16, gblk, 0, stream>>>(hidden, H2, W_o1, 1536, b_o1, nullptr,
                                          inner, 512, 512, 0);
  k_gemm16<<<512 / 16, gblk, 0, stream>>>(ctx_new, H2, W_o1 + 512, 1536, nullptr,
                                          nullptr, inner, 512, 1024, 1);
  // logits = inner @ W_o2.T + b_o2
  k_gemm16<<<V / 16, gblk, 0, stream>>>(inner, 512, W_o2, 512, b_o2, nullptr,
                                        logits, V, 512, 0);
  // vocab softmax stats, vd = p_gen*softmax (+ zero OOV tail)
  k_rowstats<<<B, 256, 0, stream>>>(logits, mz);
  k_vd<<<B, 256, 0, stream>>>(logits, mz, pgen, vd);
  // scatter-add copy distribution
  k_scatter<<<(S * B) / 256, 256, 0, stream>>>(a_out, tex, pgen, vd);
}